// Round 7
// baseline (10462.246 us; speedup 1.0000x reference)
//
#include <hip/hip_runtime.h>

typedef unsigned short u16;
typedef unsigned int u32;
typedef short v8s __attribute__((ext_vector_type(8)));
typedef float v4f __attribute__((ext_vector_type(4)));
typedef unsigned int v4u __attribute__((ext_vector_type(4)));
typedef unsigned int v2u __attribute__((ext_vector_type(2)));

#define MFMA16 __builtin_amdgcn_mfma_f32_16x16x32_bf16

constexpr int TT = 800;
constexpr int NBLK = 178;

constexpr int AUGB  = 2240;  // aug row bytes (1120 bf16: h0(0..511)|win(512..591)|stroke(592..594)|0(595)|h1prev(596..1107)|0pad)
constexpr int AUG2B = 2048;  // aug2 row bytes (1024 bf16: h1(0..511)|h2prev(512..1023))

constexpr size_t AUGR_OFF  = 16384;  // ctrl: arrive counter @0, 32 flag lines @4096+k*256
constexpr size_t AUG2R_OFF = AUGR_OFF + (size_t)4 * 64 * AUGB;
constexpr size_t WAT_OFF   = AUG2R_OFF + (size_t)4 * 64 * AUG2B;
constexpr size_t WS_ZERO   = WAT_OFF + (size_t)32 * 512 * 2;

constexpr u32 SMEM_BYTES = 82944;

__device__ __forceinline__ float bf2f(u16 u) { return __uint_as_float(((u32)u) << 16); }
__device__ __forceinline__ u16 f2bf(float f) {
    u32 x = __float_as_uint(f);
    return (u16)((x + 0x7fffu + ((x >> 16) & 1u)) >> 16);
}
__device__ __forceinline__ short f2bfs(float f) { return (short)f2bf(f); }
__device__ __forceinline__ float sigf(float x) { return 1.f / (1.f + __expf(-x)); }
__device__ __forceinline__ float tanhf2(float x) { return 1.f - 2.f / (1.f + __expf(2.f * x)); }

__device__ __forceinline__ __amdgpu_buffer_rsrc_t mkrsrc(const void* p) {
    return __builtin_amdgcn_make_buffer_rsrc((void*)p, (short)0, -1, 0x00020000);
}
// SC0|SC1 load: bypass stale L1/L2, served coherently at MALL
__device__ __forceinline__ v4u ldu4(__amdgpu_buffer_rsrc_t r, int off) {
    return __builtin_amdgcn_raw_buffer_load_b128(r, off, 0, 17);
}
// SC1 write-through stores (immediately visible at MALL)
__device__ __forceinline__ void stq8(__amdgpu_buffer_rsrc_t r, int off, u16 a, u16 b, u16 c, u16 d) {
    v2u t; t[0] = (u32)a | ((u32)b << 16); t[1] = (u32)c | ((u32)d << 16);
    __builtin_amdgcn_raw_buffer_store_b64(t, r, off, 0, 17);
}
__device__ __forceinline__ void stq4(__amdgpu_buffer_rsrc_t r, int off, u16 a, u16 b) {
    u32 t = (u32)a | ((u32)b << 16);
    __builtin_amdgcn_raw_buffer_store_b32(t, r, off, 0, 17);
}

// flat grid barrier: one monotone arrive counter + 32 distributed release flags,
// adaptive polling (first polls immediate -> detect ~= 1 MALL RTT in steady state)
__device__ __forceinline__ void gbar(u32* ctrl, u32 target) {
    __syncthreads();
    if (threadIdx.x == 0) {
        u32 old = __hip_atomic_fetch_add(ctrl, 1u, __ATOMIC_RELAXED, __HIP_MEMORY_SCOPE_AGENT);
        if (old == target * NBLK - 1) {
            #pragma unroll
            for (int k = 0; k < 32; k++)
                __hip_atomic_store(ctrl + 1024 + k * 64, target, __ATOMIC_RELAXED, __HIP_MEMORY_SCOPE_AGENT);
        } else {
            u32* gen = ctrl + 1024 + (blockIdx.x & 31) * 64;
            int sp = 0;
            while (__hip_atomic_load(gen, __ATOMIC_RELAXED, __HIP_MEMORY_SCOPE_AGENT) < target) {
                if (sp >= 2) __builtin_amdgcn_s_sleep(8);
                else if (sp == 1) __builtin_amdgcn_s_sleep(1);
                sp++;
            }
        }
    }
    __syncthreads();
}

__global__ void wat_init(const float* __restrict__ Wa, u16* __restrict__ WaT) {
    __amdgpu_buffer_rsrc_t r = mkrsrc(WaT);
    for (int idx = blockIdx.x * 256 + threadIdx.x; idx < 32 * 512 / 2; idx += gridDim.x * 256) {
        const int e0 = idx * 2, e1 = e0 + 1;
        const int n0 = e0 >> 9, k0 = e0 & 511;
        const int n1 = e1 >> 9, k1 = e1 & 511;
        const u16 a = (n0 < 30) ? f2bf(Wa[k0 * 30 + n0]) : (u16)0;
        const u16 b = (n1 < 30) ? f2bf(Wa[k1 * 30 + n1]) : (u16)0;
        stq4(r, idx * 4, a, b);
    }
}

__global__ __launch_bounds__(256, 1) void hw_main(
    const float* __restrict__ stroke, const float* __restrict__ charseq, const float* __restrict__ kappa0,
    const float* __restrict__ W0, const float* __restrict__ U0, const float* __restrict__ b0,
    const float* __restrict__ W1, const float* __restrict__ U1, const float* __restrict__ b1,
    const float* __restrict__ W2, const float* __restrict__ U2, const float* __restrict__ b2,
    const float* __restrict__ ba, const float* __restrict__ Wm, const float* __restrict__ bm,
    float* __restrict__ out, char* __restrict__ ws)
{
    extern __shared__ __align__(16) char smem[];
    u32* ctrl = (u32*)ws;
    u16* augr  = (u16*)(ws + AUGR_OFF);
    u16* aug2r = (u16*)(ws + AUG2R_OFF);
    const u16* WaT = (const u16*)(ws + WAT_OFF);

    const int blk = blockIdx.x, tid = threadIdx.x;
    const int wave = tid >> 6, lane = tid & 63;
    const int quad = lane >> 4, l15 = lane & 15;

    if (blk < 32) {
        // ------- S0: lstm0 @ t=i. 32 blocks: cs=blk&15 (32 h-cols), mg=blk>>4 (32 batches).
        // waves = gates, 2 fragment sets (16+16 cols): 128 VGPR weights, no spill.
        const int cs = blk & 15, mg = blk >> 4;
        __amdgpu_buffer_rsrc_t ra = mkrsrc(augr);
        u16*   aL  = (u16*)smem;                   // 32 rows x 1040B
        float* zb  = (float*)(smem + 33280);       // 32 x 132
        float* w0s = (float*)(smem + 50176);       // 3 x 128
        float* b0s = (float*)(smem + 51712);       // 128
        if (tid < 128) {
            const int cn2 = (tid >> 5) * 512 + cs * 32 + (tid & 31);
            b0s[tid] = b0[cn2];
            #pragma unroll
            for (int d = 0; d < 3; d++) w0s[d * 128 + tid] = W0[d * 2048 + cn2];
        }
        v8s bw0[16], bw1[16];
        {
            const int cnA = wave * 512 + cs * 32 + l15;
            const int cnB = cnA + 16;
            #pragma unroll
            for (int kc = 0; kc < 16; kc++)
                #pragma unroll
                for (int j = 0; j < 8; j++) {
                    const int k = kc * 32 + quad * 8 + j;
                    bw0[kc][j] = f2bfs(U0[k * 2048 + cnA]);
                    bw1[kc][j] = f2bfs(U0[k * 2048 + cnB]);
                }
        }
        float cst[4] = {0.f, 0.f, 0.f, 0.f};
        __syncthreads();
        #pragma unroll 1
        for (int i = 0; i <= TT + 3; i++) {
            if (i < TT) {
                const int t = i;
                {   // stage h0[t-1] (32 rows x 1024B) -> LDS
                    const int base = (((t + 3) & 3) * 64 + mg * 32) * AUGB;
                    #pragma unroll
                    for (int c8 = 0; c8 < 8; c8++) {
                        const int c = tid + 256 * c8;
                        const int row = c >> 6, off = c & 63;
                        v4u d = ldu4(ra, base + row * AUGB + off * 16);
                        *(v4u*)((char*)aL + row * 1040 + off * 16) = d;
                    }
                }
                __syncthreads();
                v4f c0a = {0,0,0,0}, c0b = {0,0,0,0}, c1a = {0,0,0,0}, c1b = {0,0,0,0};
                const int xo = quad * 16;
                #pragma unroll
                for (int kc = 0; kc < 16; kc++) {
                    v8s x0 = *(const v8s*)((const char*)aL + l15 * 1040 + kc * 64 + xo);
                    v8s x1 = *(const v8s*)((const char*)aL + (16 + l15) * 1040 + kc * 64 + xo);
                    c0a = MFMA16(x0, bw0[kc], c0a, 0, 0, 0);
                    c1a = MFMA16(x0, bw1[kc], c1a, 0, 0, 0);
                    c0b = MFMA16(x1, bw0[kc], c0b, 0, 0, 0);
                    c1b = MFMA16(x1, bw1[kc], c1b, 0, 0, 0);
                }
                const int n0 = wave * 32 + l15, n1 = n0 + 16;
                #pragma unroll
                for (int r = 0; r < 4; r++) {
                    zb[(quad * 4 + r) * 132 + n0] = c0a[r];
                    zb[(quad * 4 + r) * 132 + n1] = c1a[r];
                    zb[(16 + quad * 4 + r) * 132 + n0] = c0b[r];
                    zb[(16 + quad * 4 + r) * 132 + n1] = c1b[r];
                }
                __syncthreads();
                {   // epilogue: 32 rows x 32 h-cols, 4 cells/thread
                    const int bl = tid & 31, jj = tid >> 5;
                    const int b = mg * 32 + bl;
                    const float xx0 = stroke[(b * TT + t) * 3 + 0];
                    const float xx1 = stroke[(b * TT + t) * 3 + 1];
                    const float xx2 = stroke[(b * TT + t) * 3 + 2];
                    u16 hv[4];
                    #pragma unroll
                    for (int m = 0; m < 4; m++) {
                        const int j = jj * 4 + m;
                        float z[4];
                        #pragma unroll
                        for (int g = 0; g < 4; g++) {
                            const int n = g * 32 + j;
                            z[g] = zb[bl * 132 + n] + b0s[n] + xx0 * w0s[n] + xx1 * w0s[128 + n] + xx2 * w0s[256 + n];
                        }
                        const float cc = sigf(z[1]) * cst[m] + sigf(z[0]) * tanhf2(z[2]);
                        cst[m] = cc;
                        hv[m] = f2bf(sigf(z[3]) * tanhf2(cc));
                    }
                    stq8(ra, ((t & 3) * 64 + b) * AUGB + (cs * 32 + jj * 4) * 2, hv[0], hv[1], hv[2], hv[3]);
                }
            }
            if (i < TT + 3) gbar(ctrl, (u32)(i + 1));
        }
    } else if (blk < 96) {
        // ------- S1: lstm1 @ t1=i-2. 64 blocks: cs=q>>1 (16 h-cols), mg=q&1 (32 batches).
        // waves = gates, ONE fragment set (16 cols): 140 VGPR weights, no spill. M=32 staged.
        const int q = blk - 32, cs = q >> 1, mg = q & 1;
        __amdgpu_buffer_rsrc_t ra = mkrsrc(augr);
        __amdgpu_buffer_rsrc_t r2 = mkrsrc(aug2r);
        u16*   aL  = (u16*)smem;                   // 32 rows x 2256B = 72192
        float* zb  = (float*)(smem + 72192);       // 32 x 68 = 8704B
        float* b1s = (float*)(smem + 80896);       // 64 floats
        if (tid < 64) b1s[tid] = b1[(tid >> 4) * 512 + cs * 16 + (tid & 15)];
        v8s bw[35];
        {
            const int cn = wave * 512 + cs * 16 + l15;
            #pragma unroll
            for (int kc = 0; kc < 35; kc++)
                #pragma unroll
                for (int j = 0; j < 8; j++) {
                    const int k = kc * 32 + quad * 8 + j;
                    short v = 0;
                    if (k < 595) v = f2bfs(W1[k * 2048 + cn]);
                    else if (k >= 596 && k < 1108) v = f2bfs(U1[(k - 596) * 2048 + cn]);
                    bw[kc][j] = v;
                }
        }
        float cst[2] = {0.f, 0.f};
        __syncthreads();
        #pragma unroll 1
        for (int i = 0; i <= TT + 3; i++) {
            if (i >= 2 && i <= TT + 1) {
                const int t1 = i - 2;
                {   // stage aug[t1] (32 rows x 2240B) -> LDS
                    const int base = ((t1 & 3) * 64 + mg * 32) * AUGB;
                    #pragma unroll
                    for (int c18 = 0; c18 < 18; c18++) {
                        const int c = tid + 256 * c18;        // 0..4479
                        if (c < 4480) {
                            const int row = c / 140, off = c - row * 140;
                            v4u d = ldu4(ra, base + row * AUGB + off * 16);
                            *(v4u*)((char*)aL + row * 2256 + off * 16) = d;
                        }
                    }
                }
                __syncthreads();
                v4f c0 = {0,0,0,0}, c1 = {0,0,0,0};
                const int xo = quad * 16;
                #pragma unroll
                for (int kc = 0; kc < 35; kc++) {
                    v8s x0 = *(const v8s*)((const char*)aL + l15 * 2256 + kc * 64 + xo);
                    v8s x1 = *(const v8s*)((const char*)aL + (16 + l15) * 2256 + kc * 64 + xo);
                    c0 = MFMA16(x0, bw[kc], c0, 0, 0, 0);
                    c1 = MFMA16(x1, bw[kc], c1, 0, 0, 0);
                }
                #pragma unroll
                for (int r = 0; r < 4; r++) {
                    zb[(quad * 4 + r) * 68 + wave * 17 + l15] = c0[r];
                    zb[(16 + quad * 4 + r) * 68 + wave * 17 + l15] = c1[r];
                }
                __syncthreads();
                {   // epilogue: 32 rows x 16 h-cols, 2 cells/thread
                    const int bl = tid & 31, jj = tid >> 5;  // jj 0..7
                    const int b = mg * 32 + bl;
                    u16 hv[2];
                    #pragma unroll
                    for (int m = 0; m < 2; m++) {
                        const int j = jj * 2 + m;
                        float z[4];
                        #pragma unroll
                        for (int g = 0; g < 4; g++)
                            z[g] = zb[bl * 68 + g * 17 + j] + b1s[g * 16 + j];
                        const float cc = sigf(z[1]) * cst[m] + sigf(z[0]) * tanhf2(z[2]);
                        cst[m] = cc;
                        hv[m] = f2bf(sigf(z[3]) * tanhf2(cc));
                    }
                    stq4(ra, (((t1 + 1) & 3) * 64 + b) * AUGB + (596 + cs * 16 + jj * 2) * 2, hv[0], hv[1]);
                    stq4(r2, ((t1 & 3) * 64 + b) * AUG2B + (cs * 16 + jj * 2) * 2, hv[0], hv[1]);
                }
            }
            if (i < TT + 3) gbar(ctrl, (u32)(i + 1));
        }
    } else if (blk < 160) {
        // ------- S2: lstm2 @ t2=i-3. 64 blocks, same shape as S1 (K=1024).
        const int q = blk - 96, cs = q >> 1, mg = q & 1;
        __amdgpu_buffer_rsrc_t r2 = mkrsrc(aug2r);
        u16*   aL  = (u16*)smem;                   // 32 rows x 2064B = 66048
        float* zb  = (float*)(smem + 66048);       // 32 x 68
        float* b2s = (float*)(smem + 74752);       // 64
        if (tid < 64) b2s[tid] = b2[(tid >> 4) * 512 + cs * 16 + (tid & 15)];
        v8s bw[32];
        {
            const int cn = wave * 512 + cs * 16 + l15;
            #pragma unroll
            for (int kc = 0; kc < 32; kc++)
                #pragma unroll
                for (int j = 0; j < 8; j++) {
                    const int k = kc * 32 + quad * 8 + j;
                    bw[kc][j] = (k < 512) ? f2bfs(W2[k * 2048 + cn]) : f2bfs(U2[(k - 512) * 2048 + cn]);
                }
        }
        float cst[2] = {0.f, 0.f};
        __syncthreads();
        #pragma unroll 1
        for (int i = 0; i <= TT + 3; i++) {
            if (i >= 3 && i <= TT + 2) {
                const int t2 = i - 3;
                {   // stage aug2[t2] (32 rows x 2048B) -> LDS
                    const int base = ((t2 & 3) * 64 + mg * 32) * AUG2B;
                    #pragma unroll
                    for (int c16 = 0; c16 < 16; c16++) {
                        const int c = tid + 256 * c16;        // 0..4095
                        const int row = c >> 7, off = c & 127;
                        v4u d = ldu4(r2, base + row * AUG2B + off * 16);
                        *(v4u*)((char*)aL + row * 2064 + off * 16) = d;
                    }
                }
                __syncthreads();
                v4f c0 = {0,0,0,0}, c1 = {0,0,0,0};
                const int xo = quad * 16;
                #pragma unroll
                for (int kc = 0; kc < 32; kc++) {
                    v8s x0 = *(const v8s*)((const char*)aL + l15 * 2064 + kc * 64 + xo);
                    v8s x1 = *(const v8s*)((const char*)aL + (16 + l15) * 2064 + kc * 64 + xo);
                    c0 = MFMA16(x0, bw[kc], c0, 0, 0, 0);
                    c1 = MFMA16(x1, bw[kc], c1, 0, 0, 0);
                }
                #pragma unroll
                for (int r = 0; r < 4; r++) {
                    zb[(quad * 4 + r) * 68 + wave * 17 + l15] = c0[r];
                    zb[(16 + quad * 4 + r) * 68 + wave * 17 + l15] = c1[r];
                }
                __syncthreads();
                {
                    const int bl = tid & 31, jj = tid >> 5;
                    const int b = mg * 32 + bl;
                    u16 hv[2];
                    #pragma unroll
                    for (int m = 0; m < 2; m++) {
                        const int j = jj * 2 + m;
                        float z[4];
                        #pragma unroll
                        for (int g = 0; g < 4; g++)
                            z[g] = zb[bl * 68 + g * 17 + j] + b2s[g * 16 + j];
                        const float cc = sigf(z[1]) * cst[m] + sigf(z[0]) * tanhf2(z[2]);
                        cst[m] = cc;
                        hv[m] = f2bf(sigf(z[3]) * tanhf2(cc));
                    }
                    stq4(r2, (((t2 + 1) & 3) * 64 + b) * AUG2B + (512 + cs * 16 + jj * 2) * 2, hv[0], hv[1]);
                }
            }
            if (i < TT + 3) gbar(ctrl, (u32)(i + 1));
        }
    } else if (blk < 176) {
        // ------- SA: attention @ ta=i-1. 16 blocks, one batch per wave; h0 rows staged to LDS.
        const int a = blk - 160;
        const int b = a * 4 + wave;
        __amdgpu_buffer_rsrc_t ra = mkrsrc(augr);
        u16*   watl = (u16*)smem;                      // 32 x 520 u16 (33280B)
        u16*   hrow = (u16*)(smem + 33280);            // 4 x 520 u16 (4160B)
        float* phis = (float*)(smem + 37440);          // 4 x 80
        u16*   idxs = (u16*)(smem + 38720);            // 4 x 80
        {
            #pragma unroll
            for (int c8 = 0; c8 < 8; c8++) {
                const int c = tid + 256 * c8;
                const int row = c >> 6, off = c & 63;
                *(v4u*)((char*)watl + row * 1040 + off * 16) = *(const v4u*)(WaT + row * 512 + off * 8);
            }
        }
        #pragma unroll
        for (int rep = 0; rep < 2; rep++) {
            const int u = rep * 64 + lane;
            if (u < 80) {
                int c = 0;
                #pragma unroll 1
                for (int cc = 0; cc < 80; cc++)
                    if (charseq[b * 6400 + u * 80 + cc] > 0.5f) c = cc;
                idxs[wave * 80 + u] = (u16)c;
            }
        }
        float kap = (lane < 10) ? kappa0[b * 10 + lane] : 0.f;
        const float baf = (lane < 30) ? ba[lane] : 0.f;
        const int nn = lane & 31;
        const int k0 = (lane >> 5) * 256;
        const u16* wrow = watl + nn * 520 + k0;
        __syncthreads();
        #pragma unroll 1
        for (int i = 0; i <= TT + 3; i++) {
            if (i >= 1 && i <= TT) {
                const int ta = i - 1;
                {
                    const int row = tid >> 6, off = tid & 63;
                    v4u d = ldu4(ra, ((ta & 3) * 64 + a * 4 + row) * AUGB + off * 16);
                    *(v4u*)((char*)hrow + row * 1040 + off * 16) = d;
                }
                __syncthreads();
                float acc = 0.f;
                #pragma unroll
                for (int kk = 0; kk < 32; kk++) {
                    v8s hv = *(const v8s*)((const char*)hrow + wave * 1040 + (k0 + kk * 8) * 2);
                    v8s wv = *(const v8s*)(wrow + kk * 8);
                    #pragma unroll
                    for (int e = 0; e < 8; e++) acc += bf2f((u16)hv[e]) * bf2f((u16)wv[e]);
                }
                acc += __shfl_xor(acc, 32);
                const float abk = __expf(acc + baf);
                const float kofv = __shfl(abk, 20 + (lane < 10 ? lane : 0));
                if (lane < 10) kap += kofv;
                const float u1f = (float)lane, u2f = (float)(64 + lane);
                float p1 = 0.f, p2 = 0.f;
                #pragma unroll
                for (int kk = 0; kk < 10; kk++) {
                    const float al = __shfl(abk, kk);
                    const float be = __shfl(abk, 10 + kk);
                    const float kp = __shfl(kap, kk);
                    const float d1 = kp - u1f, d2 = kp - u2f;
                    p1 += al * __expf(-be * d1 * d1);
                    p2 += al * __expf(-be * d2 * d2);
                }
                phis[wave * 80 + lane] = p1;
                if (lane < 16) phis[wave * 80 + 64 + lane] = p2;
                __syncthreads();
                const int db = (((ta & 3) * 64 + b) * AUGB) + 512 * 2;
                if (lane < 40) {
                    const int c0 = 2 * lane;
                    float w0 = 0.f, w1 = 0.f;
                    #pragma unroll 1
                    for (int u = 0; u < 80; u++) {
                        const float pv = phis[wave * 80 + u];
                        const int ix = (int)idxs[wave * 80 + u];
                        w0 += (ix == c0)     ? pv : 0.f;
                        w1 += (ix == c0 + 1) ? pv : 0.f;
                    }
                    stq4(ra, db + c0 * 2, f2bf(w0), f2bf(w1));
                } else if (lane == 40) {
                    stq4(ra, db + 80 * 2, f2bf(stroke[(b * TT + ta) * 3 + 0]), f2bf(stroke[(b * TT + ta) * 3 + 1]));
                } else if (lane == 41) {
                    stq4(ra, db + 82 * 2, f2bf(stroke[(b * TT + ta) * 3 + 2]), (u16)0);
                }
            }
            if (i < TT + 3) gbar(ctrl, (u32)(i + 1));
        }
    } else if (blk < 178) {
        // ------- SM: MDN head @ tm=i-4. 2 blocks (32 batches each), 121 cols/block.
        const int mgs = blk - 176;
        __amdgpu_buffer_rsrc_t r2 = mkrsrc(aug2r);
        u16*   aL = (u16*)smem;                    // 32 rows x 1040B
        float* zb = (float*)(smem + 33280);        // 32 x 132
        v8s bw0[16], bw1[16];
        {
            const int nA = wave * 32 + l15, nB = nA + 16;
            #pragma unroll
            for (int kc = 0; kc < 16; kc++)
                #pragma unroll
                for (int j = 0; j < 8; j++) {
                    const int k = kc * 32 + quad * 8 + j;
                    bw0[kc][j] = (nA < 121) ? f2bfs(Wm[k * 121 + nA]) : (short)0;
                    bw1[kc][j] = (nB < 121) ? f2bfs(Wm[k * 121 + nB]) : (short)0;
                }
        }
        __syncthreads();
        #pragma unroll 1
        for (int i = 0; i <= TT + 3; i++) {
            if (i >= 4) {
                const int tm = i - 4;
                {
                    const int base = (((tm + 1) & 3) * 64 + mgs * 32) * AUG2B + 1024;
                    #pragma unroll
                    for (int c8 = 0; c8 < 8; c8++) {
                        const int c = tid + 256 * c8;
                        const int row = c >> 6, off = c & 63;
                        v4u d = ldu4(r2, base + row * AUG2B + off * 16);
                        *(v4u*)((char*)aL + row * 1040 + off * 16) = d;
                    }
                }
                __syncthreads();
                v4f c0a = {0,0,0,0}, c0b = {0,0,0,0}, c1a = {0,0,0,0}, c1b = {0,0,0,0};
                const int xo = quad * 16;
                #pragma unroll
                for (int kc = 0; kc < 16; kc++) {
                    v8s x0 = *(const v8s*)((const char*)aL + l15 * 1040 + kc * 64 + xo);
                    v8s x1 = *(const v8s*)((const char*)aL + (16 + l15) * 1040 + kc * 64 + xo);
                    c0a = MFMA16(x0, bw0[kc], c0a, 0, 0, 0);
                    c1a = MFMA16(x0, bw1[kc], c1a, 0, 0, 0);
                    c0b = MFMA16(x1, bw0[kc], c0b, 0, 0, 0);
                    c1b = MFMA16(x1, bw1[kc], c1b, 0, 0, 0);
                }
                const int n0 = wave * 32 + l15, n1 = n0 + 16;
                #pragma unroll
                for (int r = 0; r < 4; r++) {
                    zb[(quad * 4 + r) * 132 + n0] = c0a[r];
                    zb[(quad * 4 + r) * 132 + n1] = c1a[r];
                    zb[(16 + quad * 4 + r) * 132 + n0] = c0b[r];
                    zb[(16 + quad * 4 + r) * 132 + n1] = c1b[r];
                }
                __syncthreads();
                {
                    const int b8 = tid >> 3, g8 = tid & 7;
                    const int b = mgs * 32 + b8;
                    const float* zr = zb + b8 * 132;
                    float* orow = out + ((size_t)(b * TT + tm)) * 121;
                    if (g8 == 0) {
                        orow[0] = sigf(-(zr[0] + bm[0]));
                        float mx = -1e30f;
                        float zv[20];
                        #pragma unroll 1
                        for (int nl = 1; nl <= 20; nl++) { zv[nl - 1] = zr[nl] + bm[nl]; mx = fmaxf(mx, zv[nl - 1]); }
                        float ss = 0.f;
                        #pragma unroll 1
                        for (int nl = 0; nl < 20; nl++) { zv[nl] = __expf(zv[nl] - mx); ss += zv[nl]; }
                        const float inv = 1.f / ss;
                        #pragma unroll 1
                        for (int nl = 0; nl < 20; nl++) orow[nl + 1] = zv[nl] * inv;
                    } else if (g8 <= 2) {
                        const int s0 = 21 + (g8 - 1) * 20;
                        #pragma unroll 1
                        for (int nl = s0; nl < s0 + 20; nl++) orow[nl] = zr[nl] + bm[nl];
                    } else if (g8 <= 4) {
                        const int s0 = 61 + (g8 - 3) * 20;
                        #pragma unroll 1
                        for (int nl = s0; nl < s0 + 20; nl++) orow[nl] = __expf(zr[nl] + bm[nl]);
                    } else if (g8 <= 6) {
                        const int s0 = 101 + (g8 - 5) * 10;
                        #pragma unroll 1
                        for (int nl = s0; nl < s0 + 10; nl++) orow[nl] = tanhf2(zr[nl] + bm[nl]);
                    }
                }
            }
            if (i < TT + 3) gbar(ctrl, (u32)(i + 1));
        }
    }
}

extern "C" void kernel_launch(void* const* d_in, const int* in_sizes, int n_in,
                              void* d_out, int out_size, void* d_ws, size_t ws_size,
                              hipStream_t stream) {
    const float* stroke  = (const float*)d_in[0];
    const float* charseq = (const float*)d_in[1];
    const float* kappa0  = (const float*)d_in[2];
    const float* W0 = (const float*)d_in[3];
    const float* U0 = (const float*)d_in[4];
    const float* b0 = (const float*)d_in[5];
    const float* W1 = (const float*)d_in[6];
    const float* U1 = (const float*)d_in[7];
    const float* b1 = (const float*)d_in[8];
    const float* W2 = (const float*)d_in[9];
    const float* U2 = (const float*)d_in[10];
    const float* b2 = (const float*)d_in[11];
    const float* Wa = (const float*)d_in[12];
    const float* ba = (const float*)d_in[13];
    const float* Wm = (const float*)d_in[14];
    const float* bm = (const float*)d_in[15];
    char* ws = (char*)d_ws;

    static bool attr_done = false;
    if (!attr_done) {
        hipFuncSetAttribute((const void*)hw_main,
                            hipFuncAttributeMaxDynamicSharedMemorySize, SMEM_BYTES);
        attr_done = true;
    }

    hipMemsetAsync(d_ws, 0, WS_ZERO, stream);
    wat_init<<<8, 256, 0, stream>>>(Wa, (u16*)(ws + WAT_OFF));
    hw_main<<<NBLK, 256, SMEM_BYTES, stream>>>(stroke, charseq, kappa0, W0, U0, b0,
                                               W1, U1, b1, W2, U2, b2, ba, Wm, bm,
                                               (float*)d_out, ws);
}

// Round 8
// 8689.506 us; speedup vs baseline: 1.2040x; 1.2040x over previous
//
#include <hip/hip_runtime.h>

typedef unsigned short u16;
typedef unsigned int u32;
typedef short v8s __attribute__((ext_vector_type(8)));
typedef float v4f __attribute__((ext_vector_type(4)));
typedef unsigned int v4u __attribute__((ext_vector_type(4)));
typedef unsigned int v2u __attribute__((ext_vector_type(2)));

#define MFMA16 __builtin_amdgcn_mfma_f32_16x16x32_bf16

constexpr int TT = 800;
constexpr int NBLK = 178;

constexpr int AUGB  = 2240;  // aug row bytes (1120 bf16: h0(0..511)|win(512..591)|stroke(592..594)|0(595)|h1prev(596..1107)|pad)
constexpr int AUG2B = 2048;  // aug2 row bytes (1024 bf16: h1(0..511)|h2prev(512..1023))

// ctrl: 8 counter groups x [4 slots x 16 subcounters x 256B] = 128 KiB
constexpr size_t AUGR_OFF  = 131072;
constexpr size_t AUG2R_OFF = AUGR_OFF + (size_t)4 * 64 * AUGB;
constexpr size_t WAT_OFF   = AUG2R_OFF + (size_t)4 * 64 * AUG2B;
constexpr size_t WS_ZERO   = WAT_OFF + (size_t)32 * 512 * 2;

constexpr u32 SMEM_BYTES = 82944;

enum { G_S0D = 0, G_SAD = 1, G_S1D = 2, G_S2D = 3, G_S1R = 4, G_SAR = 5, G_S2R = 6, G_SMR = 7 };

__device__ __forceinline__ float bf2f(u16 u) { return __uint_as_float(((u32)u) << 16); }
__device__ __forceinline__ u16 f2bf(float f) {
    u32 x = __float_as_uint(f);
    return (u16)((x + 0x7fffu + ((x >> 16) & 1u)) >> 16);
}
__device__ __forceinline__ short f2bfs(float f) { return (short)f2bf(f); }
__device__ __forceinline__ float sigf(float x) { return 1.f / (1.f + __expf(-x)); }
__device__ __forceinline__ float tanhf2(float x) { return 1.f - 2.f / (1.f + __expf(2.f * x)); }

__device__ __forceinline__ __amdgpu_buffer_rsrc_t mkrsrc(const void* p) {
    return __builtin_amdgcn_make_buffer_rsrc((void*)p, (short)0, -1, 0x00020000);
}
// SC0|SC1 load: bypass stale L1/L2, served coherently at MALL
__device__ __forceinline__ v4u ldu4(__amdgpu_buffer_rsrc_t r, int off) {
    return __builtin_amdgcn_raw_buffer_load_b128(r, off, 0, 17);
}
// SC1 write-through stores (visible at MALL once vmcnt retires)
__device__ __forceinline__ void stq8(__amdgpu_buffer_rsrc_t r, int off, u16 a, u16 b, u16 c, u16 d) {
    v2u t; t[0] = (u32)a | ((u32)b << 16); t[1] = (u32)c | ((u32)d << 16);
    __builtin_amdgcn_raw_buffer_store_b64(t, r, off, 0, 17);
}
__device__ __forceinline__ void stq4(__amdgpu_buffer_rsrc_t r, int off, u16 a, u16 b) {
    u32 t = (u32)a | ((u32)b << 16);
    __builtin_amdgcn_raw_buffer_store_b32(t, r, off, 0, 17);
}

// ---- point-to-point sync ----------------------------------------------------
// group g, slot t&3, 16 subcounters spaced 256B. Monotone: after a stage with N
// blocks completes timestep t, sum over subcounters == N*((t>>2)+1).
__device__ __forceinline__ void publish(u32* ctrl, int g, int t, int blk) {
    __hip_atomic_fetch_add(ctrl + g * 4096 + (t & 3) * 1024 + (blk & 15) * 64, 1u,
                           __ATOMIC_RELAXED, __HIP_MEMORY_SCOPE_AGENT);
}
// wave0 checks up to 4 edges in parallel (one 16-lane cluster each), then block barrier.
__device__ __forceinline__ void wait4(u32* ctrl,
    int g0, int t0, u32 n0, int g1, int t1, u32 n1,
    int g2, int t2, u32 n2, int g3, int t3, u32 n3)
{
    if (threadIdx.x < 64) {
        const int lane = threadIdx.x;
        const int cl = lane >> 4, k = lane & 15;
        int g, tt; u32 nn;
        if (cl == 0)      { g = g0; tt = t0; nn = n0; }
        else if (cl == 1) { g = g1; tt = t1; nn = n1; }
        else if (cl == 2) { g = g2; tt = t2; nn = n2; }
        else              { g = g3; tt = t3; nn = n3; }
        const u32 tgt = (g >= 0 && tt >= 0) ? nn * (u32)((tt >> 2) + 1) : 0u;
        u32* p = (tgt > 0) ? (ctrl + g * 4096 + (tt & 3) * 1024 + k * 64) : (u32*)0;
        int sp = 0;
        for (;;) {
            u32 v = p ? __hip_atomic_load(p, __ATOMIC_RELAXED, __HIP_MEMORY_SCOPE_AGENT) : 0u;
            v += __shfl_xor(v, 1); v += __shfl_xor(v, 2);
            v += __shfl_xor(v, 4); v += __shfl_xor(v, 8);
            const bool bad = (tgt > 0) && (v < tgt);
            if (__ballot(bad) == 0ull) break;
            if (sp >= 2) __builtin_amdgcn_s_sleep(4);
            else if (sp == 1) __builtin_amdgcn_s_sleep(1);
            sp++;
        }
    }
    __syncthreads();
}

__global__ void wat_init(const float* __restrict__ Wa, u16* __restrict__ WaT) {
    __amdgpu_buffer_rsrc_t r = mkrsrc(WaT);
    for (int idx = blockIdx.x * 256 + threadIdx.x; idx < 32 * 512 / 2; idx += gridDim.x * 256) {
        const int e0 = idx * 2, e1 = e0 + 1;
        const int n0 = e0 >> 9, k0 = e0 & 511;
        const int n1 = e1 >> 9, k1 = e1 & 511;
        const u16 a = (n0 < 30) ? f2bf(Wa[k0 * 30 + n0]) : (u16)0;
        const u16 b = (n1 < 30) ? f2bf(Wa[k1 * 30 + n1]) : (u16)0;
        stq4(r, idx * 4, a, b);
    }
}

__global__ __launch_bounds__(256, 1) void hw_main(
    const float* __restrict__ stroke, const float* __restrict__ charseq, const float* __restrict__ kappa0,
    const float* __restrict__ W0, const float* __restrict__ U0, const float* __restrict__ b0,
    const float* __restrict__ W1, const float* __restrict__ U1, const float* __restrict__ b1,
    const float* __restrict__ W2, const float* __restrict__ U2, const float* __restrict__ b2,
    const float* __restrict__ ba, const float* __restrict__ Wm, const float* __restrict__ bm,
    float* __restrict__ out, char* __restrict__ ws)
{
    extern __shared__ __align__(16) char smem[];
    u32* ctrl = (u32*)ws;
    u16* augr  = (u16*)(ws + AUGR_OFF);
    u16* aug2r = (u16*)(ws + AUG2R_OFF);
    const u16* WaT = (const u16*)(ws + WAT_OFF);

    const int blk = blockIdx.x, tid = threadIdx.x;
    const int wave = tid >> 6, lane = tid & 63;
    const int quad = lane >> 4, l15 = lane & 15;

    if (blk < 32) {
        // ------- S0: lstm0. Own loop t=0..799. deps: S0d[t-1]; WAR: S1r[t-4], SAr[t-4].
        const int cs = blk & 15, mg = blk >> 4;
        __amdgpu_buffer_rsrc_t ra = mkrsrc(augr);
        u16*   aL  = (u16*)smem;                   // 32 rows x 1040B
        float* zb  = (float*)(smem + 33280);       // 32 x 132
        float* w0s = (float*)(smem + 50176);       // 3 x 128
        float* b0s = (float*)(smem + 51712);       // 128
        if (tid < 128) {
            const int cn2 = (tid >> 5) * 512 + cs * 32 + (tid & 31);
            b0s[tid] = b0[cn2];
            #pragma unroll
            for (int d = 0; d < 3; d++) w0s[d * 128 + tid] = W0[d * 2048 + cn2];
        }
        v8s bw0[16], bw1[16];
        {
            const int cnA = wave * 512 + cs * 32 + l15;
            const int cnB = cnA + 16;
            #pragma unroll
            for (int kc = 0; kc < 16; kc++)
                #pragma unroll
                for (int j = 0; j < 8; j++) {
                    const int k = kc * 32 + quad * 8 + j;
                    bw0[kc][j] = f2bfs(U0[k * 2048 + cnA]);
                    bw1[kc][j] = f2bfs(U0[k * 2048 + cnB]);
                }
        }
        float cst[4] = {0.f, 0.f, 0.f, 0.f};
        __syncthreads();
        #pragma unroll 1
        for (int t = 0; t < TT; t++) {
            wait4(ctrl, G_S0D, t - 1, 32, G_S1R, t - 4, 64, G_SAR, t - 4, 16, -1, 0, 0);
            {   // stage h0[t-1] (slot (t+3)&3, 32 rows x 1024B) -> LDS
                const int base = (((t + 3) & 3) * 64 + mg * 32) * AUGB;
                #pragma unroll
                for (int c8 = 0; c8 < 8; c8++) {
                    const int c = tid + 256 * c8;
                    const int row = c >> 6, off = c & 63;
                    v4u d = ldu4(ra, base + row * AUGB + off * 16);
                    *(v4u*)((char*)aL + row * 1040 + off * 16) = d;
                }
            }
            __syncthreads();
            v4f c0a = {0,0,0,0}, c0b = {0,0,0,0}, c1a = {0,0,0,0}, c1b = {0,0,0,0};
            const int xo = quad * 16;
            #pragma unroll
            for (int kc = 0; kc < 16; kc++) {
                v8s x0 = *(const v8s*)((const char*)aL + l15 * 1040 + kc * 64 + xo);
                v8s x1 = *(const v8s*)((const char*)aL + (16 + l15) * 1040 + kc * 64 + xo);
                c0a = MFMA16(x0, bw0[kc], c0a, 0, 0, 0);
                c1a = MFMA16(x0, bw1[kc], c1a, 0, 0, 0);
                c0b = MFMA16(x1, bw0[kc], c0b, 0, 0, 0);
                c1b = MFMA16(x1, bw1[kc], c1b, 0, 0, 0);
            }
            const int n0 = wave * 32 + l15, n1 = n0 + 16;
            #pragma unroll
            for (int r = 0; r < 4; r++) {
                zb[(quad * 4 + r) * 132 + n0] = c0a[r];
                zb[(quad * 4 + r) * 132 + n1] = c1a[r];
                zb[(16 + quad * 4 + r) * 132 + n0] = c0b[r];
                zb[(16 + quad * 4 + r) * 132 + n1] = c1b[r];
            }
            __syncthreads();
            {   // epilogue: 32 rows x 32 h-cols, 4 cells/thread
                const int bl = tid & 31, jj = tid >> 5;
                const int b = mg * 32 + bl;
                const float xx0 = stroke[(b * TT + t) * 3 + 0];
                const float xx1 = stroke[(b * TT + t) * 3 + 1];
                const float xx2 = stroke[(b * TT + t) * 3 + 2];
                u16 hv[4];
                #pragma unroll
                for (int m = 0; m < 4; m++) {
                    const int j = jj * 4 + m;
                    float z[4];
                    #pragma unroll
                    for (int g = 0; g < 4; g++) {
                        const int n = g * 32 + j;
                        z[g] = zb[bl * 132 + n] + b0s[n] + xx0 * w0s[n] + xx1 * w0s[128 + n] + xx2 * w0s[256 + n];
                    }
                    const float cc = sigf(z[1]) * cst[m] + sigf(z[0]) * tanhf2(z[2]);
                    cst[m] = cc;
                    hv[m] = f2bf(sigf(z[3]) * tanhf2(cc));
                }
                stq8(ra, ((t & 3) * 64 + b) * AUGB + (cs * 32 + jj * 4) * 2, hv[0], hv[1], hv[2], hv[3]);
            }
            __syncthreads();   // drain stores (vmcnt(0) before barrier)
            if (tid == 0) publish(ctrl, G_S0D, t, blk);
        }
    } else if (blk < 96) {
        // ------- S1: lstm1. deps: S0d[t], SAd[t], S1d[t-1]; WAR: S2r[t-4].
        const int q = blk - 32, cs = q >> 1, mg = q & 1;
        __amdgpu_buffer_rsrc_t ra = mkrsrc(augr);
        __amdgpu_buffer_rsrc_t r2 = mkrsrc(aug2r);
        u16*   aL  = (u16*)smem;                   // 32 rows x 2256B
        float* zb  = (float*)(smem + 72192);       // 32 x 68
        float* b1s = (float*)(smem + 80896);       // 64
        if (tid < 64) b1s[tid] = b1[(tid >> 4) * 512 + cs * 16 + (tid & 15)];
        v8s bw[35];
        {
            const int cn = wave * 512 + cs * 16 + l15;
            #pragma unroll
            for (int kc = 0; kc < 35; kc++)
                #pragma unroll
                for (int j = 0; j < 8; j++) {
                    const int k = kc * 32 + quad * 8 + j;
                    short v = 0;
                    if (k < 595) v = f2bfs(W1[k * 2048 + cn]);
                    else if (k >= 596 && k < 1108) v = f2bfs(U1[(k - 596) * 2048 + cn]);
                    bw[kc][j] = v;
                }
        }
        float cst[2] = {0.f, 0.f};
        __syncthreads();
        #pragma unroll 1
        for (int t = 0; t < TT; t++) {
            wait4(ctrl, G_S0D, t, 32, G_SAD, t, 16, G_S1D, t - 1, 64, G_S2R, t - 4, 64);
            {   // stage aug[t] (slot t&3, 32 rows x 2240B) -> LDS
                const int base = ((t & 3) * 64 + mg * 32) * AUGB;
                #pragma unroll
                for (int c18 = 0; c18 < 18; c18++) {
                    const int c = tid + 256 * c18;
                    if (c < 4480) {
                        const int row = c / 140, off = c - row * 140;
                        v4u d = ldu4(ra, base + row * AUGB + off * 16);
                        *(v4u*)((char*)aL + row * 2256 + off * 16) = d;
                    }
                }
            }
            __syncthreads();
            if (tid == 0) publish(ctrl, G_S1R, t, blk);
            v4f c0 = {0,0,0,0}, c1 = {0,0,0,0};
            const int xo = quad * 16;
            #pragma unroll
            for (int kc = 0; kc < 35; kc++) {
                v8s x0 = *(const v8s*)((const char*)aL + l15 * 2256 + kc * 64 + xo);
                v8s x1 = *(const v8s*)((const char*)aL + (16 + l15) * 2256 + kc * 64 + xo);
                c0 = MFMA16(x0, bw[kc], c0, 0, 0, 0);
                c1 = MFMA16(x1, bw[kc], c1, 0, 0, 0);
            }
            #pragma unroll
            for (int r = 0; r < 4; r++) {
                zb[(quad * 4 + r) * 68 + wave * 17 + l15] = c0[r];
                zb[(16 + quad * 4 + r) * 68 + wave * 17 + l15] = c1[r];
            }
            __syncthreads();
            {   // epilogue: 32 rows x 16 h-cols, 2 cells/thread
                const int bl = tid & 31, jj = tid >> 5;
                const int b = mg * 32 + bl;
                u16 hv[2];
                #pragma unroll
                for (int m = 0; m < 2; m++) {
                    const int j = jj * 2 + m;
                    float z[4];
                    #pragma unroll
                    for (int g = 0; g < 4; g++)
                        z[g] = zb[bl * 68 + g * 17 + j] + b1s[g * 16 + j];
                    const float cc = sigf(z[1]) * cst[m] + sigf(z[0]) * tanhf2(z[2]);
                    cst[m] = cc;
                    hv[m] = f2bf(sigf(z[3]) * tanhf2(cc));
                }
                stq4(ra, (((t + 1) & 3) * 64 + b) * AUGB + (596 + cs * 16 + jj * 2) * 2, hv[0], hv[1]);
                stq4(r2, ((t & 3) * 64 + b) * AUG2B + (cs * 16 + jj * 2) * 2, hv[0], hv[1]);
            }
            __syncthreads();
            if (tid == 0) publish(ctrl, G_S1D, t, blk);
        }
    } else if (blk < 160) {
        // ------- S2: lstm2. deps: S1d[t], S2d[t-1]; WAR: SMr[t-4].
        const int q = blk - 96, cs = q >> 1, mg = q & 1;
        __amdgpu_buffer_rsrc_t r2 = mkrsrc(aug2r);
        u16*   aL  = (u16*)smem;                   // 32 rows x 2064B
        float* zb  = (float*)(smem + 66048);       // 32 x 68
        float* b2s = (float*)(smem + 74752);       // 64
        if (tid < 64) b2s[tid] = b2[(tid >> 4) * 512 + cs * 16 + (tid & 15)];
        v8s bw[32];
        {
            const int cn = wave * 512 + cs * 16 + l15;
            #pragma unroll
            for (int kc = 0; kc < 32; kc++)
                #pragma unroll
                for (int j = 0; j < 8; j++) {
                    const int k = kc * 32 + quad * 8 + j;
                    bw[kc][j] = (k < 512) ? f2bfs(W2[k * 2048 + cn]) : f2bfs(U2[(k - 512) * 2048 + cn]);
                }
        }
        float cst[2] = {0.f, 0.f};
        __syncthreads();
        #pragma unroll 1
        for (int t = 0; t < TT; t++) {
            wait4(ctrl, G_S1D, t, 64, G_S2D, t - 1, 64, G_SMR, t - 4, 2, -1, 0, 0);
            {   // stage aug2[t] (slot t&3, 32 rows x 2048B) -> LDS
                const int base = ((t & 3) * 64 + mg * 32) * AUG2B;
                #pragma unroll
                for (int c16 = 0; c16 < 16; c16++) {
                    const int c = tid + 256 * c16;
                    const int row = c >> 7, off = c & 127;
                    v4u d = ldu4(r2, base + row * AUG2B + off * 16);
                    *(v4u*)((char*)aL + row * 2064 + off * 16) = d;
                }
            }
            __syncthreads();
            if (tid == 0) publish(ctrl, G_S2R, t, blk);
            v4f c0 = {0,0,0,0}, c1 = {0,0,0,0};
            const int xo = quad * 16;
            #pragma unroll
            for (int kc = 0; kc < 32; kc++) {
                v8s x0 = *(const v8s*)((const char*)aL + l15 * 2064 + kc * 64 + xo);
                v8s x1 = *(const v8s*)((const char*)aL + (16 + l15) * 2064 + kc * 64 + xo);
                c0 = MFMA16(x0, bw[kc], c0, 0, 0, 0);
                c1 = MFMA16(x1, bw[kc], c1, 0, 0, 0);
            }
            #pragma unroll
            for (int r = 0; r < 4; r++) {
                zb[(quad * 4 + r) * 68 + wave * 17 + l15] = c0[r];
                zb[(16 + quad * 4 + r) * 68 + wave * 17 + l15] = c1[r];
            }
            __syncthreads();
            {
                const int bl = tid & 31, jj = tid >> 5;
                const int b = mg * 32 + bl;
                u16 hv[2];
                #pragma unroll
                for (int m = 0; m < 2; m++) {
                    const int j = jj * 2 + m;
                    float z[4];
                    #pragma unroll
                    for (int g = 0; g < 4; g++)
                        z[g] = zb[bl * 68 + g * 17 + j] + b2s[g * 16 + j];
                    const float cc = sigf(z[1]) * cst[m] + sigf(z[0]) * tanhf2(z[2]);
                    cst[m] = cc;
                    hv[m] = f2bf(sigf(z[3]) * tanhf2(cc));
                }
                stq4(r2, (((t + 1) & 3) * 64 + b) * AUG2B + (512 + cs * 16 + jj * 2) * 2, hv[0], hv[1]);
            }
            __syncthreads();
            if (tid == 0) publish(ctrl, G_S2D, t, blk);
        }
    } else if (blk < 176) {
        // ------- SA: attention. deps: S0d[t]; WAR: S1r[t-4]. One batch per wave.
        const int a = blk - 160;
        const int b = a * 4 + wave;
        __amdgpu_buffer_rsrc_t ra = mkrsrc(augr);
        u16*   watl = (u16*)smem;                      // 32 x 520 u16
        u16*   hrow = (u16*)(smem + 33280);            // 4 x 520 u16
        float* phis = (float*)(smem + 37440);          // 4 x 80
        u16*   idxs = (u16*)(smem + 38720);            // 4 x 80
        {
            #pragma unroll
            for (int c8 = 0; c8 < 8; c8++) {
                const int c = tid + 256 * c8;
                const int row = c >> 6, off = c & 63;
                *(v4u*)((char*)watl + row * 1040 + off * 16) = *(const v4u*)(WaT + row * 512 + off * 8);
            }
        }
        #pragma unroll
        for (int rep = 0; rep < 2; rep++) {
            const int u = rep * 64 + lane;
            if (u < 80) {
                int c = 0;
                #pragma unroll 1
                for (int cc = 0; cc < 80; cc++)
                    if (charseq[b * 6400 + u * 80 + cc] > 0.5f) c = cc;
                idxs[wave * 80 + u] = (u16)c;
            }
        }
        float kap = (lane < 10) ? kappa0[b * 10 + lane] : 0.f;
        const float baf = (lane < 30) ? ba[lane] : 0.f;
        const int nn = lane & 31;
        const int k0 = (lane >> 5) * 256;
        const u16* wrow = watl + nn * 520 + k0;
        __syncthreads();
        #pragma unroll 1
        for (int t = 0; t < TT; t++) {
            wait4(ctrl, G_S0D, t, 32, G_S1R, t - 4, 64, -1, 0, 0, -1, 0, 0);
            {   // stage 4 h0[t] rows
                const int row = tid >> 6, off = tid & 63;
                v4u d = ldu4(ra, ((t & 3) * 64 + a * 4 + row) * AUGB + off * 16);
                *(v4u*)((char*)hrow + row * 1040 + off * 16) = d;
            }
            __syncthreads();
            if (tid == 0) publish(ctrl, G_SAR, t, blk);
            float acc = 0.f;
            #pragma unroll
            for (int kk = 0; kk < 32; kk++) {
                v8s hv = *(const v8s*)((const char*)hrow + wave * 1040 + (k0 + kk * 8) * 2);
                v8s wv = *(const v8s*)(wrow + kk * 8);
                #pragma unroll
                for (int e = 0; e < 8; e++) acc += bf2f((u16)hv[e]) * bf2f((u16)wv[e]);
            }
            acc += __shfl_xor(acc, 32);
            const float abk = __expf(acc + baf);
            const float kofv = __shfl(abk, 20 + (lane < 10 ? lane : 0));
            if (lane < 10) kap += kofv;
            const float u1f = (float)lane;
            float p1 = 0.f, p2 = 0.f;
            #pragma unroll
            for (int kk = 0; kk < 10; kk++) {
                const float al = __shfl(abk, kk);
                const float be = __shfl(abk, 10 + kk);
                const float kp = __shfl(kap, kk);
                const float d1 = kp - u1f, d2 = kp - (u1f + 64.f);
                p1 += al * __expf(-be * d1 * d1);
                p2 += al * __expf(-be * d2 * d2);
            }
            phis[wave * 80 + lane] = p1;
            if (lane < 16) phis[wave * 80 + 64 + lane] = p2;
            __syncthreads();
            const int db = (((t & 3) * 64 + b) * AUGB) + 512 * 2;
            if (lane < 40) {
                const int c0 = 2 * lane;
                float w0 = 0.f, w1 = 0.f;
                #pragma unroll 1
                for (int u = 0; u < 80; u++) {
                    const float pv = phis[wave * 80 + u];
                    const int ix = (int)idxs[wave * 80 + u];
                    w0 += (ix == c0)     ? pv : 0.f;
                    w1 += (ix == c0 + 1) ? pv : 0.f;
                }
                stq4(ra, db + c0 * 2, f2bf(w0), f2bf(w1));
            } else if (lane == 40) {
                stq4(ra, db + 80 * 2, f2bf(stroke[(b * TT + t) * 3 + 0]), f2bf(stroke[(b * TT + t) * 3 + 1]));
            } else if (lane == 41) {
                stq4(ra, db + 82 * 2, f2bf(stroke[(b * TT + t) * 3 + 2]), (u16)0);
            }
            __syncthreads();
            if (tid == 0) publish(ctrl, G_SAD, t, blk);
        }
    } else {
        // ------- SM: MDN head. deps: S2d[t]. 2 blocks.
        const int mgs = blk - 176;
        __amdgpu_buffer_rsrc_t r2 = mkrsrc(aug2r);
        u16*   aL = (u16*)smem;                    // 32 rows x 1040B
        float* zb = (float*)(smem + 33280);        // 32 x 132
        v8s bw0[16], bw1[16];
        {
            const int nA = wave * 32 + l15, nB = nA + 16;
            #pragma unroll
            for (int kc = 0; kc < 16; kc++)
                #pragma unroll
                for (int j = 0; j < 8; j++) {
                    const int k = kc * 32 + quad * 8 + j;
                    bw0[kc][j] = (nA < 121) ? f2bfs(Wm[k * 121 + nA]) : (short)0;
                    bw1[kc][j] = (nB < 121) ? f2bfs(Wm[k * 121 + nB]) : (short)0;
                }
        }
        __syncthreads();
        #pragma unroll 1
        for (int t = 0; t < TT; t++) {
            wait4(ctrl, G_S2D, t, 64, -1, 0, 0, -1, 0, 0, -1, 0, 0);
            {   // stage h2[t] (slot (t+1)&3, 32 rows x 1024B)
                const int base = (((t + 1) & 3) * 64 + mgs * 32) * AUG2B + 1024;
                #pragma unroll
                for (int c8 = 0; c8 < 8; c8++) {
                    const int c = tid + 256 * c8;
                    const int row = c >> 6, off = c & 63;
                    v4u d = ldu4(r2, base + row * AUG2B + off * 16);
                    *(v4u*)((char*)aL + row * 1040 + off * 16) = d;
                }
            }
            __syncthreads();
            if (tid == 0) publish(ctrl, G_SMR, t, blk);
            v4f c0a = {0,0,0,0}, c0b = {0,0,0,0}, c1a = {0,0,0,0}, c1b = {0,0,0,0};
            const int xo = quad * 16;
            #pragma unroll
            for (int kc = 0; kc < 16; kc++) {
                v8s x0 = *(const v8s*)((const char*)aL + l15 * 1040 + kc * 64 + xo);
                v8s x1 = *(const v8s*)((const char*)aL + (16 + l15) * 1040 + kc * 64 + xo);
                c0a = MFMA16(x0, bw0[kc], c0a, 0, 0, 0);
                c1a = MFMA16(x0, bw1[kc], c1a, 0, 0, 0);
                c0b = MFMA16(x1, bw0[kc], c0b, 0, 0, 0);
                c1b = MFMA16(x1, bw1[kc], c1b, 0, 0, 0);
            }
            const int n0 = wave * 32 + l15, n1 = n0 + 16;
            #pragma unroll
            for (int r = 0; r < 4; r++) {
                zb[(quad * 4 + r) * 132 + n0] = c0a[r];
                zb[(quad * 4 + r) * 132 + n1] = c1a[r];
                zb[(16 + quad * 4 + r) * 132 + n0] = c0b[r];
                zb[(16 + quad * 4 + r) * 132 + n1] = c1b[r];
            }
            __syncthreads();
            {
                const int b8 = tid >> 3, g8 = tid & 7;
                const int b = mgs * 32 + b8;
                const float* zr = zb + b8 * 132;
                float* orow = out + ((size_t)(b * TT + t)) * 121;
                if (g8 == 0) {
                    orow[0] = sigf(-(zr[0] + bm[0]));
                    float mx = -1e30f;
                    float zv[20];
                    #pragma unroll 1
                    for (int nl = 1; nl <= 20; nl++) { zv[nl - 1] = zr[nl] + bm[nl]; mx = fmaxf(mx, zv[nl - 1]); }
                    float ss = 0.f;
                    #pragma unroll 1
                    for (int nl = 0; nl < 20; nl++) { zv[nl] = __expf(zv[nl] - mx); ss += zv[nl]; }
                    const float inv = 1.f / ss;
                    #pragma unroll 1
                    for (int nl = 0; nl < 20; nl++) orow[nl + 1] = zv[nl] * inv;
                } else if (g8 <= 2) {
                    const int s0 = 21 + (g8 - 1) * 20;
                    #pragma unroll 1
                    for (int nl = s0; nl < s0 + 20; nl++) orow[nl] = zr[nl] + bm[nl];
                } else if (g8 <= 4) {
                    const int s0 = 61 + (g8 - 3) * 20;
                    #pragma unroll 1
                    for (int nl = s0; nl < s0 + 20; nl++) orow[nl] = __expf(zr[nl] + bm[nl]);
                } else if (g8 <= 6) {
                    const int s0 = 101 + (g8 - 5) * 10;
                    #pragma unroll 1
                    for (int nl = s0; nl < s0 + 10; nl++) orow[nl] = tanhf2(zr[nl] + bm[nl]);
                }
            }
            __syncthreads();
        }
    }
}

extern "C" void kernel_launch(void* const* d_in, const int* in_sizes, int n_in,
                              void* d_out, int out_size, void* d_ws, size_t ws_size,
                              hipStream_t stream) {
    const float* stroke  = (const float*)d_in[0];
    const float* charseq = (const float*)d_in[1];
    const float* kappa0  = (const float*)d_in[2];
    const float* W0 = (const float*)d_in[3];
    const float* U0 = (const float*)d_in[4];
    const float* b0 = (const float*)d_in[5];
    const float* W1 = (const float*)d_in[6];
    const float* U1 = (const float*)d_in[7];
    const float* b1 = (const float*)d_in[8];
    const float* W2 = (const float*)d_in[9];
    const float* U2 = (const float*)d_in[10];
    const float* b2 = (const float*)d_in[11];
    const float* Wa = (const float*)d_in[12];
    const float* ba = (const float*)d_in[13];
    const float* Wm = (const float*)d_in[14];
    const float* bm = (const float*)d_in[15];
    char* ws = (char*)d_ws;

    static bool attr_done = false;
    if (!attr_done) {
        hipFuncSetAttribute((const void*)hw_main,
                            hipFuncAttributeMaxDynamicSharedMemorySize, SMEM_BYTES);
        attr_done = true;
    }

    hipMemsetAsync(d_ws, 0, WS_ZERO, stream);
    wat_init<<<8, 256, 0, stream>>>(Wa, (u16*)(ws + WAT_OFF));
    hw_main<<<NBLK, 256, SMEM_BYTES, stream>>>(stroke, charseq, kappa0, W0, U0, b0,
                                               W1, U1, b1, W2, U2, b2, ba, Wm, bm,
                                               (float*)d_out, ws);
}